// Round 2
// baseline (1108.196 us; speedup 1.0000x reference)
//
#include <hip/hip_runtime.h>
#include <hip/hip_fp16.h>

typedef _Float16 f16x8 __attribute__((ext_vector_type(8)));
typedef float f32x4 __attribute__((ext_vector_type(4)));
typedef short s16x8 __attribute__((ext_vector_type(8)));

typedef __attribute__((address_space(1))) void gvoid;
typedef __attribute__((address_space(3))) void lvoid;

#define GLD_LDS16(g, l) __builtin_amdgcn_global_load_lds((gvoid*)(g), (lvoid*)(l), 16, 0, 0)

// ---- fp32 -> fp16 downcast, 8 elems/thread, 16B stores ----
__global__ __launch_bounds__(256) void cvt_f32_f16(
    const float* __restrict__ src, _Float16* __restrict__ dst, int n8)
{
    const int i = blockIdx.x * 256 + threadIdx.x;
    if (i >= n8) return;
    const float4* s = (const float4*)src;
    const float4 a = s[2 * i], b = s[2 * i + 1];
    f16x8 o;
    o[0] = (_Float16)a.x; o[1] = (_Float16)a.y; o[2] = (_Float16)a.z; o[3] = (_Float16)a.w;
    o[4] = (_Float16)b.x; o[5] = (_Float16)b.y; o[6] = (_Float16)b.z; o[7] = (_Float16)b.w;
    *(f16x8*)(dst + (size_t)i * 8) = o;
}

// C[M,N] = A[M,K] @ B[N,K]^T + bias[N]; f16 in, fp32 acc, OutT out.
// Block = 256 threads (4 waves), tile 128x128, BK=32, 16x16x32 f16 MFMA.
// grid = (N/128, M/128)
template <typename OutT>
__global__ __launch_bounds__(256) void gemm_bt_bias(
    const _Float16* __restrict__ A, int lda,
    const _Float16* __restrict__ B,        // ldb == K
    const float* __restrict__ bias,
    OutT* __restrict__ C, int ldc,
    int K)
{
    __shared__ alignas(16) _Float16 sA[128 * 32];
    __shared__ alignas(16) _Float16 sB[128 * 32];

    const int t = threadIdx.x;
    const int lane = t & 63, wave = t >> 6;
    const int m0 = blockIdx.y * 128, n0 = blockIdx.x * 128;
    const int wm = wave >> 1, wn = wave & 1;
    const int l15 = lane & 15, q4 = lane >> 4;

    const f32x4 fz = {0.f, 0.f, 0.f, 0.f};
    f32x4 acc[4][4];
#pragma unroll
    for (int i = 0; i < 4; ++i)
#pragma unroll
        for (int j = 0; j < 4; ++j) acc[i][j] = fz;

    for (int k0 = 0; k0 < K; k0 += 32) {
        // ---- stage A,B tiles (128x32 each) via async global->LDS, 16B/lane ----
#pragma unroll
        for (int it = 0; it < 2; ++it) {
            const int chunk = it * 4 + wave;      // 0..7, wave-uniform
            const int li = chunk * 64 + lane;     // 0..511
            const int row = li >> 2;              // 0..127
            const int quad = li & 3;              // 16B sub-chunk within 64B row
            const _Float16* gA = A + (size_t)(m0 + row) * lda + k0 + quad * 8;
            const _Float16* gB = B + (size_t)(n0 + row) * K + k0 + quad * 8;
            GLD_LDS16(gA, sA + chunk * 512);
            GLD_LDS16(gB, sB + chunk * 512);
        }
        __syncthreads();

        // ---- fragments + MFMA ----
        f16x8 af[4], bfr[4];
#pragma unroll
        for (int mt = 0; mt < 4; ++mt)
            af[mt] = *(const f16x8*)(sA + (wm * 64 + mt * 16 + l15) * 32 + q4 * 8);
#pragma unroll
        for (int nt = 0; nt < 4; ++nt)
            bfr[nt] = *(const f16x8*)(sB + (wn * 64 + nt * 16 + l15) * 32 + q4 * 8);
#pragma unroll
        for (int mt = 0; mt < 4; ++mt)
#pragma unroll
            for (int nt = 0; nt < 4; ++nt)
                acc[mt][nt] = __builtin_amdgcn_mfma_f32_16x16x32_f16(
                    af[mt], bfr[nt], acc[mt][nt], 0, 0, 0);
        __syncthreads();
    }

    // ---- epilogue: C/D layout col=lane&15, row=(lane>>4)*4+i ----
#pragma unroll
    for (int nt = 0; nt < 4; ++nt) {
        const int col = n0 + wn * 64 + nt * 16 + l15;
        const float bs = bias[col];
#pragma unroll
        for (int mt = 0; mt < 4; ++mt) {
#pragma unroll
            for (int i = 0; i < 4; ++i) {
                const int row = m0 + wm * 64 + mt * 16 + q4 * 4 + i;
                C[(size_t)row * ldc + col] = (OutT)(acc[mt][nt][i] + bs);
            }
        }
    }
}

// Fused attention per (b,h): scores = QK^T/sqrt(2048), causal (keep q>=k),
// softmax over the QUERY axis per key-column, O = P V. O overwrites the
// Q region of qkv (each block owns its slice). grid = 4096 blocks.
__global__ __launch_bounds__(256) void attn_fused(_Float16* __restrict__ qkv)
{
    constexpr float SCALE = 0.022097086912079608f; // 1/sqrt(2048)
    __shared__ alignas(16) char smem[55296];
    _Float16* sQ = (_Float16*)smem;              // [64][136]
    _Float16* sK = (_Float16*)(smem + 17408);    // [64][136]
    _Float16* sVT = (_Float16*)(smem + 34816);   // [128][80]  V^T
    float* sS = (float*)smem;                    // [64][65]   (reuses sQ)
    _Float16* sP = (_Float16*)(smem + 16640);    // [64][80]   (reuses sQ tail/sK)

    const int t = threadIdx.x;
    const int bh = blockIdx.x;
    const int b = bh >> 4, h = bh & 15;
    const int ld = 6144;
    const _Float16* Qg = qkv + (size_t)b * 64 * ld + h * 128;
    const _Float16* Kg = Qg + 2048;
    const _Float16* Vg = Qg + 4096;
    _Float16* Og = qkv + (size_t)b * 64 * ld + h * 128;

    // ---- load Q,K (row-major, padded) and V transposed ----
    for (int i = t; i < 1024; i += 256) {
        const int r = i >> 4, c = (i & 15) * 8;
        *(s16x8*)(sQ + r * 136 + c) = *(const s16x8*)(Qg + (size_t)r * ld + c);
        *(s16x8*)(sK + r * 136 + c) = *(const s16x8*)(Kg + (size_t)r * ld + c);
        union { s16x8 v; short s[8]; } u;
        u.v = *(const s16x8*)(Vg + (size_t)r * ld + c);
#pragma unroll
        for (int j = 0; j < 8; ++j)
            ((short*)sVT)[(c + j) * 80 + r] = u.s[j];
    }
    __syncthreads();

    const int lane = t & 63, w = t >> 6;
    const int l15 = lane & 15, q4 = lane >> 4;
    const f32x4 fz = {0.f, 0.f, 0.f, 0.f};

    // ---- scores: wave w computes q-rows [w*16, w*16+16) x all 64 keys ----
    f32x4 sc[4];
#pragma unroll
    for (int nt = 0; nt < 4; ++nt) sc[nt] = fz;
#pragma unroll
    for (int kk = 0; kk < 128; kk += 32) {
        const f16x8 aq = *(const f16x8*)(sQ + (w * 16 + l15) * 136 + kk + q4 * 8);
#pragma unroll
        for (int nt = 0; nt < 4; ++nt) {
            const f16x8 bk = *(const f16x8*)(sK + (nt * 16 + l15) * 136 + kk + q4 * 8);
            sc[nt] = __builtin_amdgcn_mfma_f32_16x16x32_f16(aq, bk, sc[nt], 0, 0, 0);
        }
    }
    __syncthreads();  // everyone done reading sQ/sK before overwrite

#pragma unroll
    for (int nt = 0; nt < 4; ++nt)
#pragma unroll
        for (int i = 0; i < 4; ++i)
            sS[(w * 16 + q4 * 4 + i) * 65 + nt * 16 + l15] = sc[nt][i] * SCALE;
    __syncthreads();

    // ---- column softmax over query axis, causal: valid q in [c, 63] ----
    if (t < 64) {
        const int c = t;
        float mx = -3.0e38f;
        for (int q = c; q < 64; ++q) mx = fmaxf(mx, sS[q * 65 + c]);
        float sum = 0.f;
        for (int q = c; q < 64; ++q) {
            const float e = __expf(sS[q * 65 + c] - mx);
            sum += e;
            sS[q * 65 + c] = e;
        }
        const float inv = 1.f / sum;
        for (int q = 0; q < 64; ++q) {
            const float p = (q >= c) ? sS[q * 65 + c] * inv : 0.f;
            sP[q * 80 + c] = (_Float16)p;
        }
    }
    __syncthreads();

    // ---- O = P @ V : wave w does q-rows [w*16,+16) x 128 dims ----
    f32x4 oa[8];
#pragma unroll
    for (int nt = 0; nt < 8; ++nt) oa[nt] = fz;
#pragma unroll
    for (int kk = 0; kk < 64; kk += 32) {
        const f16x8 ap = *(const f16x8*)(sP + (w * 16 + l15) * 80 + kk + q4 * 8);
#pragma unroll
        for (int nt = 0; nt < 8; ++nt) {
            const f16x8 bv = *(const f16x8*)(sVT + (nt * 16 + l15) * 80 + kk + q4 * 8);
            oa[nt] = __builtin_amdgcn_mfma_f32_16x16x32_f16(ap, bv, oa[nt], 0, 0, 0);
        }
    }
#pragma unroll
    for (int nt = 0; nt < 8; ++nt)
#pragma unroll
        for (int i = 0; i < 4; ++i)
            Og[(size_t)(w * 16 + q4 * 4 + i) * ld + nt * 16 + l15] =
                (_Float16)(oa[nt][i]);
}

extern "C" void kernel_launch(void* const* d_in, const int* in_sizes, int n_in,
                              void* d_out, int out_size, void* d_ws, size_t ws_size,
                              hipStream_t stream) {
    const float* x     = (const float*)d_in[0]; // [16384,2048] fp32
    const float* W_qkv = (const float*)d_in[1]; // [6144,2048]  fp32
    const float* b_qkv = (const float*)d_in[2]; // [6144]       fp32
    const float* W_out = (const float*)d_in[3]; // [2048,2048]  fp32
    const float* b_out = (const float*)d_in[4]; // [2048]       fp32
    float* out = (float*)d_out;                 // [16384,2048] fp32

    // ws layout (bytes): [0: qkv f16, 201326592) [xh f16, +67108864)
    //                    [wqh f16, +25165824)  (W_out reuses wqh slot after GEMM1)
    char* ws = (char*)d_ws;
    _Float16* qkv = (_Float16*)ws;
    _Float16* xh  = (_Float16*)(ws + 201326592);
    _Float16* wqh = (_Float16*)(ws + 268435456);
    _Float16* woh = wqh;  // reuse after GEMM1 consumed W_qkv

    // 0) downcast inputs
    cvt_f32_f16<<<dim3(33554432 / 2048), 256, 0, stream>>>(x, xh, 33554432 / 8);
    cvt_f32_f16<<<dim3(12582912 / 2048), 256, 0, stream>>>(W_qkv, wqh, 12582912 / 8);
    // 1) qkv = x @ W_qkv^T + b_qkv   (f16 out into ws)
    gemm_bt_bias<_Float16><<<dim3(48, 128), 256, 0, stream>>>(
        xh, 2048, wqh, b_qkv, qkv, 6144, 2048);
    // 1b) downcast W_out into the dead W_qkv slot
    cvt_f32_f16<<<dim3(4194304 / 2048), 256, 0, stream>>>(W_out, woh, 4194304 / 8);
    // 2) fused attention per (b,h); output overwrites q-region of qkv
    attn_fused<<<dim3(4096), 256, 0, stream>>>(qkv);
    // 3) out = attn_out @ W_out^T + b_out  (fp32 out)
    gemm_bt_bias<float><<<dim3(16, 128), 256, 0, stream>>>(
        qkv, 6144, woh, b_out, out, 2048, 2048);
}

// Round 3
// 1065.956 us; speedup vs baseline: 1.0396x; 1.0396x over previous
//
#include <hip/hip_runtime.h>
#include <hip/hip_fp16.h>

typedef _Float16 f16x8 __attribute__((ext_vector_type(8)));
typedef float f32x4 __attribute__((ext_vector_type(4)));
typedef float f32x16 __attribute__((ext_vector_type(16)));
typedef short s16x8 __attribute__((ext_vector_type(8)));

typedef __attribute__((address_space(1))) void gvoid;
typedef __attribute__((address_space(3))) void lvoid;

#define GLD_LDS16(g, l) __builtin_amdgcn_global_load_lds((gvoid*)(g), (lvoid*)(l), 16, 0, 0)

// ---- fp32 -> fp16 downcast, 8 elems/thread, 16B stores ----
__global__ __launch_bounds__(256) void cvt_f32_f16(
    const float* __restrict__ src, _Float16* __restrict__ dst, int n8)
{
    const int i = blockIdx.x * 256 + threadIdx.x;
    if (i >= n8) return;
    const float4* s = (const float4*)src;
    const float4 a = s[2 * i], b = s[2 * i + 1];
    f16x8 o;
    o[0] = (_Float16)a.x; o[1] = (_Float16)a.y; o[2] = (_Float16)a.z; o[3] = (_Float16)a.w;
    o[4] = (_Float16)b.x; o[5] = (_Float16)b.y; o[6] = (_Float16)b.z; o[7] = (_Float16)b.w;
    *(f16x8*)(dst + (size_t)i * 8) = o;
}

// C[M,N] = A[M,K] @ B[N,K]^T + bias[N]; f16 in, fp32 acc, OutT out.
// Block = 256 threads (4 waves), tile 128x128, BK=32, 32x32x16 f16 MFMA,
// 2x2 32x32 tiles per wave. LDS K-chunks XOR-swizzled: chunk' = chunk ^
// ((row>>1)&3) -> conflict-free ds_read_b128 (2 lanes/bank-group).
// grid = (N/128, M/128)
template <typename OutT>
__global__ __launch_bounds__(256) void gemm_bt_bias(
    const _Float16* __restrict__ A, int lda,
    const _Float16* __restrict__ B,        // ldb == K
    const float* __restrict__ bias,
    OutT* __restrict__ C, int ldc,
    int K)
{
    __shared__ alignas(16) _Float16 sA[128 * 32];
    __shared__ alignas(16) _Float16 sB[128 * 32];

    const int t = threadIdx.x;
    const int lane = t & 63, wave = t >> 6;
    const int m0 = blockIdx.y * 128, n0 = blockIdx.x * 128;
    const int wm = wave >> 1, wn = wave & 1;
    const int l31 = lane & 31, kh = lane >> 5;

    f32x16 acc[2][2];
#pragma unroll
    for (int i = 0; i < 2; ++i)
#pragma unroll
        for (int j = 0; j < 2; ++j)
#pragma unroll
            for (int r = 0; r < 16; ++r) acc[i][j][r] = 0.f;

    // ---- staging sources: lane li fetches the global chunk that belongs in
    // its fixed LDS slot under the XOR swizzle ----
    const int li0 = wave * 64 + lane;        // chunks 0..3 (rows 0..63)
    const int li1 = li0 + 256;               // chunks 4..7 (rows 64..127)
    const int r0 = li0 >> 2, c0 = (li0 & 3) ^ ((r0 >> 1) & 3);
    const int r1 = li1 >> 2, c1 = (li1 & 3) ^ ((r1 >> 1) & 3);
    const _Float16* gA0 = A + (size_t)(m0 + r0) * lda + c0 * 8;
    const _Float16* gA1 = A + (size_t)(m0 + r1) * lda + c1 * 8;
    const _Float16* gB0 = B + (size_t)(n0 + r0) * K + c0 * 8;
    const _Float16* gB1 = B + (size_t)(n0 + r1) * K + c1 * 8;

    // ---- fragment read offsets (f16 units), swizzle-adjusted ----
    const int sw = (l31 >> 1) & 3;
    const int arow = (wm * 64 + l31) * 32;
    const int brow = (wn * 64 + l31) * 32;
    const int o0 = ((0 * 2 + kh) ^ sw) * 8;   // k-half 0: chunk kh
    const int o1 = ((1 * 2 + kh) ^ sw) * 8;   // k-half 1: chunk 2+kh

    for (int k0 = 0; k0 < K; k0 += 32) {
        GLD_LDS16(gA0, sA + wave * 512);
        GLD_LDS16(gB0, sB + wave * 512);
        GLD_LDS16(gA1, sA + wave * 512 + 2048);
        GLD_LDS16(gB1, sB + wave * 512 + 2048);
        gA0 += 32; gA1 += 32; gB0 += 32; gB1 += 32;
        __syncthreads();

        const f16x8 a0k0 = *(const f16x8*)(sA + arow + o0);
        const f16x8 a0k1 = *(const f16x8*)(sA + arow + o1);
        const f16x8 a1k0 = *(const f16x8*)(sA + arow + 1024 + o0);
        const f16x8 a1k1 = *(const f16x8*)(sA + arow + 1024 + o1);
        const f16x8 b0k0 = *(const f16x8*)(sB + brow + o0);
        const f16x8 b0k1 = *(const f16x8*)(sB + brow + o1);
        const f16x8 b1k0 = *(const f16x8*)(sB + brow + 1024 + o0);
        const f16x8 b1k1 = *(const f16x8*)(sB + brow + 1024 + o1);

        acc[0][0] = __builtin_amdgcn_mfma_f32_32x32x16_f16(a0k0, b0k0, acc[0][0], 0, 0, 0);
        acc[0][1] = __builtin_amdgcn_mfma_f32_32x32x16_f16(a0k0, b1k0, acc[0][1], 0, 0, 0);
        acc[1][0] = __builtin_amdgcn_mfma_f32_32x32x16_f16(a1k0, b0k0, acc[1][0], 0, 0, 0);
        acc[1][1] = __builtin_amdgcn_mfma_f32_32x32x16_f16(a1k0, b1k0, acc[1][1], 0, 0, 0);
        acc[0][0] = __builtin_amdgcn_mfma_f32_32x32x16_f16(a0k1, b0k1, acc[0][0], 0, 0, 0);
        acc[0][1] = __builtin_amdgcn_mfma_f32_32x32x16_f16(a0k1, b1k1, acc[0][1], 0, 0, 0);
        acc[1][0] = __builtin_amdgcn_mfma_f32_32x32x16_f16(a1k1, b0k1, acc[1][0], 0, 0, 0);
        acc[1][1] = __builtin_amdgcn_mfma_f32_32x32x16_f16(a1k1, b1k1, acc[1][1], 0, 0, 0);
        __syncthreads();
    }

    // ---- epilogue: 32x32 C/D layout col=lane&31, row=(reg&3)+8*(reg>>2)+4*(lane>>5) ----
#pragma unroll
    for (int nt = 0; nt < 2; ++nt) {
        const int col = n0 + wn * 64 + nt * 32 + l31;
        const float bs = bias[col];
#pragma unroll
        for (int mt = 0; mt < 2; ++mt) {
#pragma unroll
            for (int reg = 0; reg < 16; ++reg) {
                const int row = m0 + wm * 64 + mt * 32 + 4 * kh + (reg & 3) + 8 * (reg >> 2);
                C[(size_t)row * ldc + col] = (OutT)(acc[mt][nt][reg] + bs);
            }
        }
    }
}

// Fused attention per (b,h): scores = QK^T/sqrt(2048), causal (keep q>=k),
// softmax over the QUERY axis per key-column, O = P V. O overwrites the
// Q region of qkv (each block owns its slice). grid = 4096 blocks.
__global__ __launch_bounds__(256) void attn_fused(_Float16* __restrict__ qkv)
{
    constexpr float SCALE = 0.022097086912079608f; // 1/sqrt(2048)
    __shared__ alignas(16) char smem[55296];
    __shared__ float sRedA[256], sRedB[256];
    _Float16* sQ = (_Float16*)smem;              // [64][136]
    _Float16* sK = (_Float16*)(smem + 17408);    // [64][136]
    _Float16* sVT = (_Float16*)(smem + 34816);   // [128][80]  V^T
    float* sSt = (float*)smem;                   // [64][65]   scores TRANSPOSED [key][query] (reuses sQ)
    _Float16* sP = (_Float16*)(smem + 16640);    // [64][80]   P[q][k] (reuses sQ tail/sK)

    const int t = threadIdx.x;
    const int bh = blockIdx.x;
    const int b = bh >> 4, h = bh & 15;
    const int ld = 6144;
    const _Float16* Qg = qkv + (size_t)b * 64 * ld + h * 128;
    const _Float16* Kg = Qg + 2048;
    const _Float16* Vg = Qg + 4096;
    _Float16* Og = qkv + (size_t)b * 64 * ld + h * 128;

    // ---- load Q,K (row-major, padded) and V transposed ----
    for (int i = t; i < 1024; i += 256) {
        const int r = i >> 4, c = (i & 15) * 8;
        *(s16x8*)(sQ + r * 136 + c) = *(const s16x8*)(Qg + (size_t)r * ld + c);
        *(s16x8*)(sK + r * 136 + c) = *(const s16x8*)(Kg + (size_t)r * ld + c);
        union { s16x8 v; short s[8]; } u;
        u.v = *(const s16x8*)(Vg + (size_t)r * ld + c);
#pragma unroll
        for (int j = 0; j < 8; ++j)
            ((short*)sVT)[(c + j) * 80 + r] = u.s[j];
    }
    __syncthreads();

    const int lane = t & 63, w = t >> 6;
    const int l15 = lane & 15, q4 = lane >> 4;
    const f32x4 fz = {0.f, 0.f, 0.f, 0.f};

    // ---- scores: wave w computes q-rows [w*16, w*16+16) x all 64 keys ----
    f32x4 sc[4];
#pragma unroll
    for (int nt = 0; nt < 4; ++nt) sc[nt] = fz;
#pragma unroll
    for (int kk = 0; kk < 128; kk += 32) {
        const f16x8 aq = *(const f16x8*)(sQ + (w * 16 + l15) * 136 + kk + q4 * 8);
#pragma unroll
        for (int nt = 0; nt < 4; ++nt) {
            const f16x8 bk = *(const f16x8*)(sK + (nt * 16 + l15) * 136 + kk + q4 * 8);
            sc[nt] = __builtin_amdgcn_mfma_f32_16x16x32_f16(aq, bk, sc[nt], 0, 0, 0);
        }
    }
    __syncthreads();  // everyone done reading sQ/sK before overwrite

    // write scores transposed: sSt[key][query]
#pragma unroll
    for (int nt = 0; nt < 4; ++nt)
#pragma unroll
        for (int i = 0; i < 4; ++i)
            sSt[(nt * 16 + l15) * 65 + (w * 16 + q4 * 4 + i)] = sc[nt][i] * SCALE;
    __syncthreads();

    // ---- column softmax over query axis (parallel: 4 threads per key) ----
    // key k = t>>2, sub-chunk j = t&3 covering q in [j*16, j*16+16)
    {
        const int k = t >> 2, j = t & 3;
        const int qlo = max(k, j * 16), qhi = min(64, j * 16 + 16);
        float mx = -3.0e38f;
        for (int q = qlo; q < qhi; ++q) mx = fmaxf(mx, sSt[k * 65 + q]);
        sRedA[t] = mx;
        __syncthreads();
        mx = fmaxf(fmaxf(sRedA[k * 4 + 0], sRedA[k * 4 + 1]),
                   fmaxf(sRedA[k * 4 + 2], sRedA[k * 4 + 3]));
        float sum = 0.f;
        for (int q = qlo; q < qhi; ++q) {
            const float e = __expf(sSt[k * 65 + q] - mx);
            sSt[k * 65 + q] = e;
            sum += e;
        }
        sRedB[t] = sum;
        __syncthreads();
        const float inv = 1.f / (sRedB[k * 4 + 0] + sRedB[k * 4 + 1] +
                                 sRedB[k * 4 + 2] + sRedB[k * 4 + 3]);
        for (int q = j * 16; q < j * 16 + 16; ++q) {
            const float p = (q >= k) ? sSt[k * 65 + q] * inv : 0.f;
            sP[q * 80 + k] = (_Float16)p;
        }
    }
    __syncthreads();

    // ---- O = P @ V : wave w does q-rows [w*16,+16) x 128 dims ----
    f32x4 oa[8];
#pragma unroll
    for (int nt = 0; nt < 8; ++nt) oa[nt] = fz;
#pragma unroll
    for (int kk = 0; kk < 64; kk += 32) {
        const f16x8 ap = *(const f16x8*)(sP + (w * 16 + l15) * 80 + kk + q4 * 8);
#pragma unroll
        for (int nt = 0; nt < 8; ++nt) {
            const f16x8 bv = *(const f16x8*)(sVT + (nt * 16 + l15) * 80 + kk + q4 * 8);
            oa[nt] = __builtin_amdgcn_mfma_f32_16x16x32_f16(ap, bv, oa[nt], 0, 0, 0);
        }
    }
#pragma unroll
    for (int nt = 0; nt < 8; ++nt)
#pragma unroll
        for (int i = 0; i < 4; ++i)
            Og[(size_t)(w * 16 + q4 * 4 + i) * ld + nt * 16 + l15] =
                (_Float16)(oa[nt][i]);
}

extern "C" void kernel_launch(void* const* d_in, const int* in_sizes, int n_in,
                              void* d_out, int out_size, void* d_ws, size_t ws_size,
                              hipStream_t stream) {
    const float* x     = (const float*)d_in[0]; // [16384,2048] fp32
    const float* W_qkv = (const float*)d_in[1]; // [6144,2048]  fp32
    const float* b_qkv = (const float*)d_in[2]; // [6144]       fp32
    const float* W_out = (const float*)d_in[3]; // [2048,2048]  fp32
    const float* b_out = (const float*)d_in[4]; // [2048]       fp32
    float* out = (float*)d_out;                 // [16384,2048] fp32

    // ws layout (bytes): [0: qkv f16, 201326592) [xh f16, +67108864)
    //                    [wqh f16, +25165824)  (W_out reuses wqh slot after GEMM1)
    char* ws = (char*)d_ws;
    _Float16* qkv = (_Float16*)ws;
    _Float16* xh  = (_Float16*)(ws + 201326592);
    _Float16* wqh = (_Float16*)(ws + 268435456);
    _Float16* woh = wqh;  // reuse after GEMM1 consumed W_qkv

    // 0) downcast inputs
    cvt_f32_f16<<<dim3(33554432 / 2048), 256, 0, stream>>>(x, xh, 33554432 / 8);
    cvt_f32_f16<<<dim3(12582912 / 2048), 256, 0, stream>>>(W_qkv, wqh, 12582912 / 8);
    // 1) qkv = x @ W_qkv^T + b_qkv   (f16 out into ws)
    gemm_bt_bias<_Float16><<<dim3(48, 128), 256, 0, stream>>>(
        xh, 2048, wqh, b_qkv, qkv, 6144, 2048);
    // 1b) downcast W_out into the dead W_qkv slot
    cvt_f32_f16<<<dim3(4194304 / 2048), 256, 0, stream>>>(W_out, woh, 4194304 / 8);
    // 2) fused attention per (b,h); output overwrites q-region of qkv
    attn_fused<<<dim3(4096), 256, 0, stream>>>(qkv);
    // 3) out = attn_out @ W_out^T + b_out  (fp32 out)
    gemm_bt_bias<float><<<dim3(16, 128), 256, 0, stream>>>(
        qkv, 6144, woh, b_out, out, 2048, 2048);
}

// Round 4
// 967.041 us; speedup vs baseline: 1.1460x; 1.1023x over previous
//
#include <hip/hip_runtime.h>
#include <hip/hip_fp16.h>

typedef _Float16 f16x8 __attribute__((ext_vector_type(8)));
typedef _Float16 f16x2 __attribute__((ext_vector_type(2)));
typedef float f32x4 __attribute__((ext_vector_type(4)));
typedef float f32x16 __attribute__((ext_vector_type(16)));
typedef short s16x8 __attribute__((ext_vector_type(8)));

typedef __attribute__((address_space(1))) void gvoid;
typedef __attribute__((address_space(3))) void lvoid;

#define GLD_LDS16(g, l) __builtin_amdgcn_global_load_lds((gvoid*)(g), (lvoid*)(l), 16, 0, 0)

// ---- fp32 -> fp16 downcast, 8 elems/thread, 16B stores ----
__global__ __launch_bounds__(256) void cvt_f32_f16(
    const float* __restrict__ src, _Float16* __restrict__ dst, int n8)
{
    const int i = blockIdx.x * 256 + threadIdx.x;
    if (i >= n8) return;
    const float4* s = (const float4*)src;
    const float4 a = s[2 * i], b = s[2 * i + 1];
    f16x8 o;
    o[0] = (_Float16)a.x; o[1] = (_Float16)a.y; o[2] = (_Float16)a.z; o[3] = (_Float16)a.w;
    o[4] = (_Float16)b.x; o[5] = (_Float16)b.y; o[6] = (_Float16)b.z; o[7] = (_Float16)b.w;
    *(f16x8*)(dst + (size_t)i * 8) = o;
}

// C[M,N] = A[M,K] @ B[N,K]^T + bias[N]; f16 in, fp32 acc, OutT out.
// Block = 256 threads (4 waves), tile 128x128, BK=64 (16 MFMA/barrier),
// 32x32x16 f16 MFMA, 2x2 tiles/wave. Rows are 8 x 16B chunks; LDS chunks
// XOR-swizzled c' = c ^ (row&7) -> 4-way max on fragment ds_read_b128.
// __launch_bounds__(256,4): cap regs at 128 (64 AGPR + <=64 VGPR) -> 4 blk/CU.
// grid = (N/128, M/128)
template <typename OutT>
__global__ __launch_bounds__(256, 4) void gemm_bt_bias(
    const _Float16* __restrict__ A, int lda,
    const _Float16* __restrict__ B,        // ldb == K
    const float* __restrict__ bias,
    OutT* __restrict__ C, int ldc,
    int K)
{
    __shared__ alignas(16) _Float16 sA[128 * 64];
    __shared__ alignas(16) _Float16 sB[128 * 64];

    const int t = threadIdx.x;
    const int lane = t & 63, wave = t >> 6;
    const int m0 = blockIdx.y * 128, n0 = blockIdx.x * 128;
    const int wm = wave >> 1, wn = wave & 1;
    const int l31 = lane & 31, kh = lane >> 5;

    f32x16 acc[2][2];
#pragma unroll
    for (int i = 0; i < 2; ++i)
#pragma unroll
        for (int j = 0; j < 2; ++j)
#pragma unroll
            for (int r = 0; r < 16; ++r) acc[i][j][r] = 0.f;

    // staging: 4 GLDs/wave/tile; slot s=(wave*4+g)*64+lane -> row=s>>3,
    // phys chunk=s&7, logical chunk fetched = phys ^ (row&7)
    const _Float16* gA[4];
    const _Float16* gB[4];
#pragma unroll
    for (int g = 0; g < 4; ++g) {
        const int s = (wave * 4 + g) * 64 + lane;
        const int r = s >> 3;
        const int c = (s & 7) ^ (r & 7);
        gA[g] = A + (size_t)(m0 + r) * lda + c * 8;
        gB[g] = B + (size_t)(n0 + r) * K + c * 8;
    }

    const int ar0 = wm * 64 + l31, ar1 = ar0 + 32;
    const int br0 = wn * 64 + l31, br1 = br0 + 32;
    const int swa = ar0 & 7, swb = br0 & 7;   // +32 doesn't change &7

    for (int k0 = 0; k0 < K; k0 += 64) {
#pragma unroll
        for (int g = 0; g < 4; ++g) {
            GLD_LDS16(gA[g], sA + (wave * 4 + g) * 512);
            GLD_LDS16(gB[g], sB + (wave * 4 + g) * 512);
            gA[g] += 64; gB[g] += 64;
        }
        __syncthreads();

#pragma unroll
        for (int s = 0; s < 4; ++s) {
            const int ck = 2 * s + kh;
            const f16x8 a0 = *(const f16x8*)(sA + ar0 * 64 + ((ck ^ swa) * 8));
            const f16x8 a1 = *(const f16x8*)(sA + ar1 * 64 + ((ck ^ swa) * 8));
            const f16x8 b0 = *(const f16x8*)(sB + br0 * 64 + ((ck ^ swb) * 8));
            const f16x8 b1 = *(const f16x8*)(sB + br1 * 64 + ((ck ^ swb) * 8));
            acc[0][0] = __builtin_amdgcn_mfma_f32_32x32x16_f16(a0, b0, acc[0][0], 0, 0, 0);
            acc[0][1] = __builtin_amdgcn_mfma_f32_32x32x16_f16(a0, b1, acc[0][1], 0, 0, 0);
            acc[1][0] = __builtin_amdgcn_mfma_f32_32x32x16_f16(a1, b0, acc[1][0], 0, 0, 0);
            acc[1][1] = __builtin_amdgcn_mfma_f32_32x32x16_f16(a1, b1, acc[1][1], 0, 0, 0);
        }
        __syncthreads();
    }

    // ---- epilogue: 32x32 C/D layout col=lane&31, row=(reg&3)+8*(reg>>2)+4*(lane>>5) ----
#pragma unroll
    for (int nt = 0; nt < 2; ++nt) {
        const int col = n0 + wn * 64 + nt * 32 + l31;
        const float bs = bias[col];
#pragma unroll
        for (int mt = 0; mt < 2; ++mt) {
#pragma unroll
            for (int reg = 0; reg < 16; ++reg) {
                const int row = m0 + wm * 64 + mt * 32 + 4 * kh + (reg & 3) + 8 * (reg >> 2);
                C[(size_t)row * ldc + col] = (OutT)(acc[mt][nt][reg] + bs);
            }
        }
    }
}

// Fused attention per (b,h): scores = QK^T/sqrt(2048), causal (keep q>=k),
// softmax over the QUERY axis per key-column, O = P V. O overwrites the
// Q region of qkv. V kept ROW-MAJOR stride 134 (odd dwords -> full bank
// spread); PV B-frags built from 8 scalar ds_read_u16 at 2-way (free).
// LDS 53 KB -> 3 blocks/CU. grid = 4096 blocks.
__global__ __launch_bounds__(256) void attn_fused(_Float16* __restrict__ qkv)
{
    constexpr float SCALE = 0.022097086912079608f; // 1/sqrt(2048)
    __shared__ alignas(16) char smem[51968];
    __shared__ float sRed[256];
    _Float16* sQ = (_Float16*)smem;              // [64][136]
    _Float16* sK = (_Float16*)(smem + 17408);    // [64][136]
    _Float16* sV = (_Float16*)(smem + 34816);    // [64][134] row-major
    float* sSt = (float*)smem;                   // [64][65] scores [key][q] (reuses sQ)
    _Float16* sP = (_Float16*)(smem + 17408);    // [64][72]  P[q][k] (reuses sK)

    const int t = threadIdx.x;
    const int bh = blockIdx.x;
    const int b = bh >> 4, h = bh & 15;
    const int ld = 6144;
    const _Float16* Qg = qkv + (size_t)b * 64 * ld + h * 128;
    const _Float16* Kg = Qg + 2048;
    const _Float16* Vg = Qg + 4096;
    _Float16* Og = qkv + (size_t)b * 64 * ld + h * 128;

    // ---- load Q,K padded row-major; V row-major stride 134 ----
    for (int i = t; i < 1024; i += 256) {
        const int r = i >> 4, c = (i & 15) * 8;
        *(s16x8*)(sQ + r * 136 + c) = *(const s16x8*)(Qg + (size_t)r * ld + c);
        *(s16x8*)(sK + r * 136 + c) = *(const s16x8*)(Kg + (size_t)r * ld + c);
        const f16x8 vv = *(const f16x8*)(Vg + (size_t)r * ld + c);
#pragma unroll
        for (int p = 0; p < 4; ++p) {
            f16x2 w2; w2[0] = vv[2 * p]; w2[1] = vv[2 * p + 1];
            *(f16x2*)(sV + r * 134 + c + 2 * p) = w2;
        }
    }
    __syncthreads();

    const int lane = t & 63, w = t >> 6;
    const int l15 = lane & 15, q4 = lane >> 4;
    const f32x4 fz = {0.f, 0.f, 0.f, 0.f};

    // ---- scores: wave w computes q-rows [w*16, w*16+16) x all 64 keys ----
    f32x4 sc[4];
#pragma unroll
    for (int nt = 0; nt < 4; ++nt) sc[nt] = fz;
#pragma unroll
    for (int kk = 0; kk < 128; kk += 32) {
        const f16x8 aq = *(const f16x8*)(sQ + (w * 16 + l15) * 136 + kk + q4 * 8);
#pragma unroll
        for (int nt = 0; nt < 4; ++nt) {
            const f16x8 bk = *(const f16x8*)(sK + (nt * 16 + l15) * 136 + kk + q4 * 8);
            sc[nt] = __builtin_amdgcn_mfma_f32_16x16x32_f16(aq, bk, sc[nt], 0, 0, 0);
        }
    }
    __syncthreads();  // done reading sQ/sK before overwrite

    // write scores transposed: sSt[key][query]
#pragma unroll
    for (int nt = 0; nt < 4; ++nt)
#pragma unroll
        for (int i = 0; i < 4; ++i)
            sSt[(nt * 16 + l15) * 65 + (w * 16 + q4 * 4 + i)] = sc[nt][i] * SCALE;
    __syncthreads();

    // ---- column softmax over query axis (4 threads per key column) ----
    {
        const int k = t >> 2, j = t & 3;
        const int qlo = max(k, j * 16), qhi = min(64, j * 16 + 16);
        float mx = -3.0e38f;
        for (int q = qlo; q < qhi; ++q) mx = fmaxf(mx, sSt[k * 65 + q]);
        sRed[t] = mx;
        __syncthreads();
        mx = fmaxf(fmaxf(sRed[k * 4 + 0], sRed[k * 4 + 1]),
                   fmaxf(sRed[k * 4 + 2], sRed[k * 4 + 3]));
        float sum = 0.f;
        for (int q = qlo; q < qhi; ++q) {
            const float e = __expf(sSt[k * 65 + q] - mx);
            sSt[k * 65 + q] = e;
            sum += e;
        }
        sRed[t] = sum;   // safe: group reads above are wave-lockstep, own entries only
        __syncthreads();
        const float inv = 1.f / (sRed[k * 4 + 0] + sRed[k * 4 + 1] +
                                 sRed[k * 4 + 2] + sRed[k * 4 + 3]);
        for (int q = j * 16; q < j * 16 + 16; ++q) {
            const float p = (q >= k) ? sSt[k * 65 + q] * inv : 0.f;
            sP[q * 72 + k] = (_Float16)p;
        }
    }
    __syncthreads();

    // ---- O = P @ V : wave w does q-rows [w*16,+16) x 128 dims ----
    f32x4 oa[8];
#pragma unroll
    for (int nt = 0; nt < 8; ++nt) oa[nt] = fz;
#pragma unroll
    for (int kk = 0; kk < 64; kk += 32) {
        const f16x8 ap = *(const f16x8*)(sP + (w * 16 + l15) * 72 + kk + q4 * 8);
#pragma unroll
        for (int nt = 0; nt < 8; ++nt) {
            f16x8 bv;
#pragma unroll
            for (int j = 0; j < 8; ++j)
                bv[j] = sV[(kk + q4 * 8 + j) * 134 + nt * 16 + l15];
            oa[nt] = __builtin_amdgcn_mfma_f32_16x16x32_f16(ap, bv, oa[nt], 0, 0, 0);
        }
    }
#pragma unroll
    for (int nt = 0; nt < 8; ++nt)
#pragma unroll
        for (int i = 0; i < 4; ++i)
            Og[(size_t)(w * 16 + q4 * 4 + i) * ld + nt * 16 + l15] =
                (_Float16)(oa[nt][i]);
}

extern "C" void kernel_launch(void* const* d_in, const int* in_sizes, int n_in,
                              void* d_out, int out_size, void* d_ws, size_t ws_size,
                              hipStream_t stream) {
    const float* x     = (const float*)d_in[0]; // [16384,2048] fp32
    const float* W_qkv = (const float*)d_in[1]; // [6144,2048]  fp32
    const float* b_qkv = (const float*)d_in[2]; // [6144]       fp32
    const float* W_out = (const float*)d_in[3]; // [2048,2048]  fp32
    const float* b_out = (const float*)d_in[4]; // [2048]       fp32
    float* out = (float*)d_out;                 // [16384,2048] fp32

    char* ws = (char*)d_ws;
    _Float16* qkv = (_Float16*)ws;                    // [16384,6144] f16
    _Float16* xh  = (_Float16*)(ws + 201326592);      // [16384,2048] f16
    _Float16* wqh = (_Float16*)(ws + 268435456);      // [6144,2048]  f16
    _Float16* woh = wqh;  // W_out reuses slot after GEMM1 consumed W_qkv

    // 0) downcast inputs
    cvt_f32_f16<<<dim3(33554432 / 2048), 256, 0, stream>>>(x, xh, 33554432 / 8);
    cvt_f32_f16<<<dim3(12582912 / 2048), 256, 0, stream>>>(W_qkv, wqh, 12582912 / 8);
    // 1) qkv = x @ W_qkv^T + b_qkv   (f16 out into ws)
    gemm_bt_bias<_Float16><<<dim3(48, 128), 256, 0, stream>>>(
        xh, 2048, wqh, b_qkv, qkv, 6144, 2048);
    // 1b) downcast W_out into the dead W_qkv slot
    cvt_f32_f16<<<dim3(4194304 / 2048), 256, 0, stream>>>(W_out, woh, 4194304 / 8);
    // 2) fused attention per (b,h); output overwrites q-region of qkv
    attn_fused<<<dim3(4096), 256, 0, stream>>>(qkv);
    // 3) out = attn_out @ W_out^T + b_out  (fp32 out)
    gemm_bt_bias<float><<<dim3(16, 128), 256, 0, stream>>>(
        qkv, 6144, woh, b_out, out, 2048, 2048);
}